// Round 1
// baseline (428.674 us; speedup 1.0000x reference)
//
#include <hip/hip_runtime.h>

#define N_ROWS 500000
#define Q0 50000
#define Q1 10000

// ws layout (floats)
#define S0_OFF 0
#define C0_OFF (Q0 * 16)              // 800000
#define S1_OFF (C0_OFF + Q0)          // 850000
#define C1_OFF (S1_OFF + Q1 * 16)     // 1010000
#define WS_FLOATS (C1_OFF + Q1)       // 1020000

__global__ __launch_bounds__(256) void zero_ws_kernel(float* __restrict__ ws) {
    int i = blockIdx.x * 256 + threadIdx.x;
    if (i < WS_FLOATS) ws[i] = 0.0f;
}

// One thread per (row, dim) pair: 500000*16 = 8M threads.
__global__ __launch_bounds__(256) void scatter_kernel(const float* __restrict__ emb0,
                                                      const float* __restrict__ emb1,
                                                      const int* __restrict__ z0,
                                                      const int* __restrict__ z1,
                                                      float* __restrict__ ws) {
    int t = blockIdx.x * 256 + threadIdx.x;
    if (t >= N_ROWS * 16) return;
    int row = t >> 4;
    int d = t & 15;
    int a0 = z0[row];
    int a1 = z1[row];
    atomicAdd(ws + S0_OFF + a0 * 16 + d, emb0[t]);
    atomicAdd(ws + S1_OFF + a1 * 16 + d, emb1[t]);
    if (d == 0) {
        atomicAdd(ws + C0_OFF + a0, 1.0f);
        atomicAdd(ws + C1_OFF + a1, 1.0f);
    }
}

// Fused gather + segment-mean divide + 3-layer MLP. One thread per row.
__global__ __launch_bounds__(256) void mlp_kernel(const float* __restrict__ X,
                                                  const int* __restrict__ z0,
                                                  const int* __restrict__ z1,
                                                  const float* __restrict__ ws,
                                                  const float* __restrict__ W1,
                                                  const float* __restrict__ b1,
                                                  const float* __restrict__ W2,
                                                  const float* __restrict__ b2,
                                                  const float* __restrict__ Wout,
                                                  const float* __restrict__ bout,
                                                  float* __restrict__ out) {
    // W1t[j][m] = W1[m][j], row stride 68 floats (=272B, 16B-aligned, breaks
    // the stride-64 bank aliasing on the one-time transpose write).
    __shared__ __align__(16) float W1t[128 * 68];
    __shared__ __align__(16) float W2s[128 * 64];   // [k][j], row-major as given
    __shared__ float b1s[128];
    __shared__ float b2s[64];
    __shared__ float Wo[64];
    __shared__ float bo;

    for (int i = threadIdx.x; i < 128 * 64; i += 256) {
        float w1 = W1[i];            // i = m*128 + j (coalesced global read)
        int m = i >> 7;
        int j = i & 127;
        W1t[j * 68 + m] = w1;
        W2s[i] = W2[i];
    }
    if (threadIdx.x < 128) {
        b1s[threadIdx.x] = b1[threadIdx.x];
    } else if (threadIdx.x < 192) {
        b2s[threadIdx.x - 128] = b2[threadIdx.x - 128];
    } else {
        Wo[threadIdx.x - 192] = Wout[threadIdx.x - 192];
    }
    if (threadIdx.x == 0) bo = bout[0];
    __syncthreads();

    int row = blockIdx.x * 256 + threadIdx.x;
    if (row >= N_ROWS) return;

    float hin[64];
    {
        const float4* X4 = (const float4*)(X + (size_t)row * 32);
#pragma unroll
        for (int q = 0; q < 8; q++) {
            float4 v = X4[q];
            hin[q * 4 + 0] = v.x; hin[q * 4 + 1] = v.y;
            hin[q * 4 + 2] = v.z; hin[q * 4 + 3] = v.w;
        }
        int a0 = z0[row];
        float inv0 = 1.0f / ws[C0_OFF + a0];   // count >= 1 for any gathered bucket
        const float4* s04 = (const float4*)(ws + S0_OFF + a0 * 16);
#pragma unroll
        for (int q = 0; q < 4; q++) {
            float4 v = s04[q];
            hin[32 + q * 4 + 0] = v.x * inv0; hin[32 + q * 4 + 1] = v.y * inv0;
            hin[32 + q * 4 + 2] = v.z * inv0; hin[32 + q * 4 + 3] = v.w * inv0;
        }
        int a1 = z1[row];
        float inv1 = 1.0f / ws[C1_OFF + a1];
        const float4* s14 = (const float4*)(ws + S1_OFF + a1 * 16);
#pragma unroll
        for (int q = 0; q < 4; q++) {
            float4 v = s14[q];
            hin[48 + q * 4 + 0] = v.x * inv1; hin[48 + q * 4 + 1] = v.y * inv1;
            hin[48 + q * 4 + 2] = v.z * inv1; hin[48 + q * 4 + 3] = v.w * inv1;
        }
    }

    float h2[64];
#pragma unroll
    for (int j = 0; j < 64; j++) h2[j] = b2s[j];

    // Stream h1[k] one at a time: dot(hin, W1t[k]) -> relu -> rank-1 update of h2.
    for (int k = 0; k < 128; k++) {
        const float4* w1r = (const float4*)(&W1t[k * 68]);
        float p0 = 0.f, p1 = 0.f, p2 = 0.f, p3 = 0.f;
#pragma unroll
        for (int m = 0; m < 16; m++) {
            float4 w = w1r[m];
            p0 = fmaf(hin[m * 4 + 0], w.x, p0);
            p1 = fmaf(hin[m * 4 + 1], w.y, p1);
            p2 = fmaf(hin[m * 4 + 2], w.z, p2);
            p3 = fmaf(hin[m * 4 + 3], w.w, p3);
        }
        float h1k = fmaxf(b1s[k] + ((p0 + p1) + (p2 + p3)), 0.0f);
        const float4* w2r = (const float4*)(&W2s[k * 64]);
#pragma unroll
        for (int j = 0; j < 16; j++) {
            float4 w = w2r[j];
            h2[j * 4 + 0] = fmaf(h1k, w.x, h2[j * 4 + 0]);
            h2[j * 4 + 1] = fmaf(h1k, w.y, h2[j * 4 + 1]);
            h2[j * 4 + 2] = fmaf(h1k, w.z, h2[j * 4 + 2]);
            h2[j * 4 + 3] = fmaf(h1k, w.w, h2[j * 4 + 3]);
        }
    }

    float acc = bo;
#pragma unroll
    for (int j = 0; j < 64; j++) acc = fmaf(fmaxf(h2[j], 0.0f), Wo[j], acc);
    out[row] = acc;
}

extern "C" void kernel_launch(void* const* d_in, const int* in_sizes, int n_in,
                              void* d_out, int out_size, void* d_ws, size_t ws_size,
                              hipStream_t stream) {
    const float* X    = (const float*)d_in[0];
    const int*   z0   = (const int*)d_in[1];
    const int*   z1   = (const int*)d_in[2];
    const float* emb0 = (const float*)d_in[3];
    const float* emb1 = (const float*)d_in[4];
    const float* W1   = (const float*)d_in[5];
    const float* b1   = (const float*)d_in[6];
    const float* W2   = (const float*)d_in[7];
    const float* b2   = (const float*)d_in[8];
    const float* Wout = (const float*)d_in[9];
    const float* bout = (const float*)d_in[10];
    float* out = (float*)d_out;
    float* ws  = (float*)d_ws;

    zero_ws_kernel<<<(WS_FLOATS + 255) / 256, 256, 0, stream>>>(ws);
    scatter_kernel<<<(N_ROWS * 16 + 255) / 256, 256, 0, stream>>>(emb0, emb1, z0, z1, ws);
    mlp_kernel<<<(N_ROWS + 255) / 256, 256, 0, stream>>>(X, z0, z1, ws, W1, b1, W2, b2,
                                                         Wout, bout, out);
}

// Round 2
// 169.510 us; speedup vs baseline: 2.5289x; 2.5289x over previous
//
#include <hip/hip_runtime.h>
#include <stdint.h>

#define N_ROWS 500000
#define Q0 50000
#define Q1 10000
#define NTILES (N_ROWS / 16)          // 31250 exactly

// ws layout (floats)
#define S0_OFF 0
#define C0_OFF (Q0 * 16)              // 800000
#define S1_OFF (C0_OFF + Q0)          // 850000
#define C1_OFF (S1_OFF + Q1 * 16)     // 1010000
#define WS_FLOATS (C1_OFF + Q1)       // 1020000

typedef __attribute__((ext_vector_type(8))) short bf16x8;   // 8 bf16 (4 VGPRs)
typedef __attribute__((ext_vector_type(4))) float f32x4;

static __device__ __forceinline__ short f2bf(float f) {
    uint32_t u = __builtin_bit_cast(uint32_t, f);
    u += 0x7fffu + ((u >> 16) & 1u);          // round-to-nearest-even
    return (short)(u >> 16);
}

__global__ __launch_bounds__(256) void zero_ws_kernel(float* __restrict__ ws) {
    int i = blockIdx.x * 256 + threadIdx.x;
    if (i < WS_FLOATS) ws[i] = 0.0f;
}

// One thread per (row, dim): 8M threads, coalesced emb reads, atomic scatter.
__global__ __launch_bounds__(256) void scatter_kernel(const float* __restrict__ emb0,
                                                      const float* __restrict__ emb1,
                                                      const int* __restrict__ z0,
                                                      const int* __restrict__ z1,
                                                      float* __restrict__ ws) {
    int t = blockIdx.x * 256 + threadIdx.x;
    if (t >= N_ROWS * 16) return;
    int row = t >> 4;
    int d = t & 15;
    int a0 = z0[row];
    int a1 = z1[row];
    atomicAdd(ws + S0_OFF + a0 * 16 + d, emb0[t]);
    atomicAdd(ws + S1_OFF + a1 * 16 + d, emb1[t]);
    if (d == 0) {
        atomicAdd(ws + C0_OFF + a0, 1.0f);
        atomicAdd(ws + C1_OFF + a1, 1.0f);
    }
}

// Fused gather + segment-mean + 3-layer MLP using bf16 MFMA.
// One wave = one 16-row tile per iteration; grid-stride over the 31250 tiles.
// A/B frags share the same (g,e)->k map so any K-permutation error cancels.
__global__ __launch_bounds__(256, 2) void mlp_mfma_kernel(
    const float* __restrict__ X, const int* __restrict__ z0, const int* __restrict__ z1,
    const float* __restrict__ ws,
    const float* __restrict__ W1, const float* __restrict__ b1,
    const float* __restrict__ W2, const float* __restrict__ b2,
    const float* __restrict__ Wout, const float* __restrict__ bout,
    float* __restrict__ out)
{
    __shared__ float h1s[4][16 * 128];        // per-wave private transpose buffer (8 KB each)
    const int lane = threadIdx.x & 63;
    const int wv = threadIdx.x >> 6;
    const int c = lane & 15;                  // A-row / B-col / D-col index
    const int g = lane >> 4;                  // k-group
    float* h1w = h1s[wv];

    // ---- build B-fragments for W1 (8 col-tiles x 2 k-steps) and W2 (4 x 4) in registers
    bf16x8 w1f[8][2];
#pragma unroll
    for (int ct = 0; ct < 8; ct++)
#pragma unroll
        for (int ks = 0; ks < 2; ks++)
#pragma unroll
            for (int e = 0; e < 8; e++)
                w1f[ct][ks][e] = f2bf(W1[(ks * 32 + g * 8 + e) * 128 + ct * 16 + c]);

    bf16x8 w2f[4][4];
#pragma unroll
    for (int ct = 0; ct < 4; ct++)
#pragma unroll
        for (int ks = 0; ks < 4; ks++)
#pragma unroll
            for (int e = 0; e < 8; e++)
                w2f[ct][ks][e] = f2bf(W2[(ks * 32 + g * 8 + e) * 64 + ct * 16 + c]);

    float b1v[8], b2v[4], wo[4];
#pragma unroll
    for (int ct = 0; ct < 8; ct++) b1v[ct] = b1[ct * 16 + c];
#pragma unroll
    for (int ct = 0; ct < 4; ct++) b2v[ct] = b2[ct * 16 + c];
#pragma unroll
    for (int t = 0; t < 4; t++) wo[t] = Wout[t * 16 + c];
    const float bo = bout[0];

    // emb-gather routing for the k=32..63 fragment: g<2 -> emb0-mean, g>=2 -> emb1-mean
    const int gg = g * 8;
    const bool is0 = (gg < 16);
    const int* zp = is0 ? z0 : z1;
    const int coff = is0 ? C0_OFF : C1_OFF;
    const int soff = is0 ? S0_OFF : S1_OFF;
    const int esub = gg & 8;

    // ---- swizzled LDS addressing (XOR bits 2-3 of dword index with row&3)
    int waddr[4];                             // write: rows g*4+r, col c (+ct*16 imm)
#pragma unroll
    for (int r = 0; r < 4; r++) {
        int rowl = g * 4 + r;
        waddr[r] = rowl * 128 + (c ^ ((rowl & 3) << 2));
    }
    const int xr = (c & 3) << 2;              // read: row c, feats g*8+e (+ks*32)
    const int lo0 = ((g & 1) << 3) ^ xr;
    const int rbase0 = c * 128 + ((g >> 1) << 4) + lo0;
    const int rbase1 = c * 128 + ((g >> 1) << 4) + (lo0 ^ 4);

    const int wave_id = blockIdx.x * 4 + wv;
    const int nw = gridDim.x * 4;

    for (int tile = wave_id; tile < NTILES; tile += nw) {
        const int row = tile * 16 + c;

        // ---- A1 fragments: k 0..31 from X, k 32..63 from segment means
        bf16x8 a1[2];
        const float4* xp = (const float4*)(X + (size_t)row * 32 + gg);
        float4 x0 = xp[0], x1 = xp[1];
        a1[0][0] = f2bf(x0.x); a1[0][1] = f2bf(x0.y);
        a1[0][2] = f2bf(x0.z); a1[0][3] = f2bf(x0.w);
        a1[0][4] = f2bf(x1.x); a1[0][5] = f2bf(x1.y);
        a1[0][6] = f2bf(x1.z); a1[0][7] = f2bf(x1.w);

        int a = zp[row];
        float inv = 1.0f / ws[coff + a];      // count >= 1 for any referenced bucket
        const float4* ep = (const float4*)(ws + soff + a * 16 + esub);
        float4 e0 = ep[0], e1 = ep[1];
        a1[1][0] = f2bf(e0.x * inv); a1[1][1] = f2bf(e0.y * inv);
        a1[1][2] = f2bf(e0.z * inv); a1[1][3] = f2bf(e0.w * inv);
        a1[1][4] = f2bf(e1.x * inv); a1[1][5] = f2bf(e1.y * inv);
        a1[1][6] = f2bf(e1.z * inv); a1[1][7] = f2bf(e1.w * inv);

        // ---- layer 1: D1[ct] = A1 @ W1[:, ct*16..+16] + b1
        f32x4 d1[8];
#pragma unroll
        for (int ct = 0; ct < 8; ct++) {
            f32x4 acc = {b1v[ct], b1v[ct], b1v[ct], b1v[ct]};
            acc = __builtin_amdgcn_mfma_f32_16x16x32_bf16(a1[0], w1f[ct][0], acc, 0, 0, 0);
            acc = __builtin_amdgcn_mfma_f32_16x16x32_bf16(a1[1], w1f[ct][1], acc, 0, 0, 0);
            d1[ct] = acc;
        }

        // ---- relu + transpose via swizzled LDS (wave-private, no barrier needed)
#pragma unroll
        for (int ct = 0; ct < 8; ct++)
#pragma unroll
            for (int r = 0; r < 4; r++)
                h1w[waddr[r] + ct * 16] = fmaxf(d1[ct][r], 0.0f);

        // ---- A2 fragments from LDS (2 x b128 per k-step, bank-floor-optimal)
        bf16x8 a2[4];
#pragma unroll
        for (int ks = 0; ks < 4; ks++) {
            f32x4 p0 = *(const f32x4*)&h1w[rbase0 + ks * 32];
            f32x4 p1 = *(const f32x4*)&h1w[rbase1 + ks * 32];
            a2[ks][0] = f2bf(p0[0]); a2[ks][1] = f2bf(p0[1]);
            a2[ks][2] = f2bf(p0[2]); a2[ks][3] = f2bf(p0[3]);
            a2[ks][4] = f2bf(p1[0]); a2[ks][5] = f2bf(p1[1]);
            a2[ks][6] = f2bf(p1[2]); a2[ks][7] = f2bf(p1[3]);
        }

        // ---- layer 2: D2[ct] = relu(h1) @ W2[:, ct*16..+16] + b2
        f32x4 d2[4];
#pragma unroll
        for (int ct = 0; ct < 4; ct++) {
            f32x4 acc = {b2v[ct], b2v[ct], b2v[ct], b2v[ct]};
#pragma unroll
            for (int ks = 0; ks < 4; ks++)
                acc = __builtin_amdgcn_mfma_f32_16x16x32_bf16(a2[ks], w2f[ct][ks], acc, 0, 0, 0);
            d2[ct] = acc;
        }

        // ---- layer 3 on VALU + 16-lane butterfly reduce + store
        float sr[4];
#pragma unroll
        for (int r = 0; r < 4; r++) {
            float s = 0.0f;
#pragma unroll
            for (int ct = 0; ct < 4; ct++)
                s = fmaf(fmaxf(d2[ct][r], 0.0f), wo[ct], s);
            sr[r] = s;
        }
#pragma unroll
        for (int m = 1; m <= 8; m <<= 1)
#pragma unroll
            for (int r = 0; r < 4; r++)
                sr[r] += __shfl_xor(sr[r], m);
        if (c == 0) {
            float4 o = {sr[0] + bo, sr[1] + bo, sr[2] + bo, sr[3] + bo};
            *(float4*)(out + tile * 16 + g * 4) = o;
        }
    }
}

extern "C" void kernel_launch(void* const* d_in, const int* in_sizes, int n_in,
                              void* d_out, int out_size, void* d_ws, size_t ws_size,
                              hipStream_t stream) {
    const float* X    = (const float*)d_in[0];
    const int*   z0   = (const int*)d_in[1];
    const int*   z1   = (const int*)d_in[2];
    const float* emb0 = (const float*)d_in[3];
    const float* emb1 = (const float*)d_in[4];
    const float* W1   = (const float*)d_in[5];
    const float* b1   = (const float*)d_in[6];
    const float* W2   = (const float*)d_in[7];
    const float* b2   = (const float*)d_in[8];
    const float* Wout = (const float*)d_in[9];
    const float* bout = (const float*)d_in[10];
    float* out = (float*)d_out;
    float* ws  = (float*)d_ws;

    zero_ws_kernel<<<(WS_FLOATS + 255) / 256, 256, 0, stream>>>(ws);
    scatter_kernel<<<(N_ROWS * 16 + 255) / 256, 256, 0, stream>>>(emb0, emb1, z0, z1, ws);
    mlp_mfma_kernel<<<512, 256, 0, stream>>>(X, z0, z1, ws, W1, b1, W2, b2, Wout, bout, out);
}

// Round 3
// 165.658 us; speedup vs baseline: 2.5877x; 1.0233x over previous
//
#include <hip/hip_runtime.h>
#include <stdint.h>

#define N_ROWS 500000
#define Q0 50000
#define Q1 10000
#define NTILES (N_ROWS / 16)          // 31250 exactly

// per-replica ws layout (floats). After finalize_kernel, replica 0's S0/S1
// slots hold the segment MEANS (divide_no_nan applied).
#define S0_OFF 0
#define C0_OFF (Q0 * 16)              // 800000
#define S1_OFF (C0_OFF + Q0)          // 850000
#define C1_OFF (S1_OFF + Q1 * 16)     // 1010000
#define WS_FLOATS (C1_OFF + Q1)       // 1020000

typedef __attribute__((ext_vector_type(8))) short bf16x8;   // 8 bf16 (4 VGPRs)
typedef __attribute__((ext_vector_type(4))) float f32x4;

static __device__ __forceinline__ short f2bf(float f) {
    uint32_t u = __builtin_bit_cast(uint32_t, f);
    u += 0x7fffu + ((u >> 16) & 1u);          // round-to-nearest-even
    return (short)(u >> 16);
}

__global__ __launch_bounds__(256) void zero_ws_kernel(float* __restrict__ ws, int total) {
    int stride = gridDim.x * 256;
    for (int i = blockIdx.x * 256 + threadIdx.x; i < total; i += stride) ws[i] = 0.0f;
}

// One thread per (row, dim): 8M threads. Atomic scatter into one of `rep_mask+1`
// replica tables chosen by blockIdx&mask (tracks round-robin block->XCD mapping,
// keeping each replica's lines in one XCD's L2 and cutting same-address contention).
__global__ __launch_bounds__(256) void scatter_kernel(const float* __restrict__ emb0,
                                                      const float* __restrict__ emb1,
                                                      const int* __restrict__ z0,
                                                      const int* __restrict__ z1,
                                                      float* __restrict__ ws,
                                                      int rep_mask) {
    int t = blockIdx.x * 256 + threadIdx.x;
    if (t >= N_ROWS * 16) return;
    float* base = ws + (size_t)(blockIdx.x & rep_mask) * WS_FLOATS;
    int row = t >> 4;
    int d = t & 15;
    int a0 = z0[row];
    int a1 = z1[row];
    atomicAdd(base + S0_OFF + a0 * 16 + d, emb0[t]);
    atomicAdd(base + S1_OFF + a1 * 16 + d, emb1[t]);
    if (d == 0) {
        atomicAdd(base + C0_OFF + a0, 1.0f);
        atomicAdd(base + C1_OFF + a1, 1.0f);
    }
}

// Sum replicas, divide_no_nan, write means into replica 0's sum slots.
__global__ __launch_bounds__(256) void finalize_kernel(float* __restrict__ ws, int reps) {
    int b = blockIdx.x * 256 + threadIdx.x;      // bucket id across both tables
    if (b >= Q0 + Q1) return;
    int soff = (b < Q0) ? (S0_OFF + b * 16) : (S1_OFF + (b - Q0) * 16);
    int coff = (b < Q0) ? (C0_OFF + b) : (C1_OFF + (b - Q0));
    float4 s0 = {0, 0, 0, 0}, s1 = {0, 0, 0, 0}, s2 = {0, 0, 0, 0}, s3 = {0, 0, 0, 0};
    float c = 0.0f;
    for (int r = 0; r < reps; r++) {
        const float* base = ws + (size_t)r * WS_FLOATS;
        const float4* sp = (const float4*)(base + soff);
        float4 v0 = sp[0], v1 = sp[1], v2 = sp[2], v3 = sp[3];
        s0.x += v0.x; s0.y += v0.y; s0.z += v0.z; s0.w += v0.w;
        s1.x += v1.x; s1.y += v1.y; s1.z += v1.z; s1.w += v1.w;
        s2.x += v2.x; s2.y += v2.y; s2.z += v2.z; s2.w += v2.w;
        s3.x += v3.x; s3.y += v3.y; s3.z += v3.z; s3.w += v3.w;
        c += base[coff];
    }
    float inv = (c > 0.0f) ? (1.0f / c) : 0.0f;   // divide_no_nan
    float4* op = (float4*)(ws + soff);
    float4 o0 = {s0.x * inv, s0.y * inv, s0.z * inv, s0.w * inv};
    float4 o1 = {s1.x * inv, s1.y * inv, s1.z * inv, s1.w * inv};
    float4 o2 = {s2.x * inv, s2.y * inv, s2.z * inv, s2.w * inv};
    float4 o3 = {s3.x * inv, s3.y * inv, s3.z * inv, s3.w * inv};
    op[0] = o0; op[1] = o1; op[2] = o2; op[3] = o3;
}

// Fused gather + 3-layer MLP using bf16 MFMA. One wave = one 16-row tile.
__global__ __launch_bounds__(256, 2) void mlp_mfma_kernel(
    const float* __restrict__ X, const int* __restrict__ z0, const int* __restrict__ z1,
    const float* __restrict__ ws,
    const float* __restrict__ W1, const float* __restrict__ b1,
    const float* __restrict__ W2, const float* __restrict__ b2,
    const float* __restrict__ Wout, const float* __restrict__ bout,
    float* __restrict__ out)
{
    __shared__ float h1s[4][16 * 128];        // per-wave private transpose buffer (8 KB each)
    const int lane = threadIdx.x & 63;
    const int wv = threadIdx.x >> 6;
    const int c = lane & 15;                  // A-row / B-col / D-col index
    const int g = lane >> 4;                  // k-group
    float* h1w = h1s[wv];

    // ---- build B-fragments for W1 (8 col-tiles x 2 k-steps) and W2 (4 x 4) in registers
    bf16x8 w1f[8][2];
#pragma unroll
    for (int ct = 0; ct < 8; ct++)
#pragma unroll
        for (int ks = 0; ks < 2; ks++)
#pragma unroll
            for (int e = 0; e < 8; e++)
                w1f[ct][ks][e] = f2bf(W1[(ks * 32 + g * 8 + e) * 128 + ct * 16 + c]);

    bf16x8 w2f[4][4];
#pragma unroll
    for (int ct = 0; ct < 4; ct++)
#pragma unroll
        for (int ks = 0; ks < 4; ks++)
#pragma unroll
            for (int e = 0; e < 8; e++)
                w2f[ct][ks][e] = f2bf(W2[(ks * 32 + g * 8 + e) * 64 + ct * 16 + c]);

    float b1v[8], b2v[4], wo[4];
#pragma unroll
    for (int ct = 0; ct < 8; ct++) b1v[ct] = b1[ct * 16 + c];
#pragma unroll
    for (int ct = 0; ct < 4; ct++) b2v[ct] = b2[ct * 16 + c];
#pragma unroll
    for (int t = 0; t < 4; t++) wo[t] = Wout[t * 16 + c];
    const float bo = bout[0];

    // emb-gather routing for the k=32..63 fragment: g<2 -> mean0, g>=2 -> mean1
    const int gg = g * 8;
    const bool is0 = (gg < 16);
    const int* zp = is0 ? z0 : z1;
    const int soff = is0 ? S0_OFF : S1_OFF;
    const int esub = gg & 8;

    // ---- swizzled LDS addressing (XOR bits 2-3 of dword index with row&3)
    int waddr[4];                             // write: rows g*4+r, col c (+ct*16 imm)
#pragma unroll
    for (int r = 0; r < 4; r++) {
        int rowl = g * 4 + r;
        waddr[r] = rowl * 128 + (c ^ ((rowl & 3) << 2));
    }
    const int xr = (c & 3) << 2;              // read: row c, feats g*8+e (+ks*32)
    const int lo0 = ((g & 1) << 3) ^ xr;
    const int rbase0 = c * 128 + ((g >> 1) << 4) + lo0;
    const int rbase1 = c * 128 + ((g >> 1) << 4) + (lo0 ^ 4);

    const int wave_id = blockIdx.x * 4 + wv;
    const int nw = gridDim.x * 4;

    for (int tile = wave_id; tile < NTILES; tile += nw) {
        const int row = tile * 16 + c;

        // ---- A1 fragments: k 0..31 from X, k 32..63 from the mean tables
        bf16x8 a1[2];
        const float4* xp = (const float4*)(X + (size_t)row * 32 + gg);
        float4 x0 = xp[0], x1 = xp[1];
        a1[0][0] = f2bf(x0.x); a1[0][1] = f2bf(x0.y);
        a1[0][2] = f2bf(x0.z); a1[0][3] = f2bf(x0.w);
        a1[0][4] = f2bf(x1.x); a1[0][5] = f2bf(x1.y);
        a1[0][6] = f2bf(x1.z); a1[0][7] = f2bf(x1.w);

        int a = zp[row];
        const float4* ep = (const float4*)(ws + soff + a * 16 + esub);
        float4 e0 = ep[0], e1 = ep[1];
        a1[1][0] = f2bf(e0.x); a1[1][1] = f2bf(e0.y);
        a1[1][2] = f2bf(e0.z); a1[1][3] = f2bf(e0.w);
        a1[1][4] = f2bf(e1.x); a1[1][5] = f2bf(e1.y);
        a1[1][6] = f2bf(e1.z); a1[1][7] = f2bf(e1.w);

        // ---- layer 1: D1[ct] = A1 @ W1[:, ct*16..+16] + b1
        f32x4 d1[8];
#pragma unroll
        for (int ct = 0; ct < 8; ct++) {
            f32x4 acc = {b1v[ct], b1v[ct], b1v[ct], b1v[ct]};
            acc = __builtin_amdgcn_mfma_f32_16x16x32_bf16(a1[0], w1f[ct][0], acc, 0, 0, 0);
            acc = __builtin_amdgcn_mfma_f32_16x16x32_bf16(a1[1], w1f[ct][1], acc, 0, 0, 0);
            d1[ct] = acc;
        }

        // ---- relu + transpose via swizzled LDS (wave-private, no barrier needed)
#pragma unroll
        for (int ct = 0; ct < 8; ct++)
#pragma unroll
            for (int r = 0; r < 4; r++)
                h1w[waddr[r] + ct * 16] = fmaxf(d1[ct][r], 0.0f);

        // ---- A2 fragments from LDS (2 x b128 per k-step, bank-floor-optimal)
        bf16x8 a2[4];
#pragma unroll
        for (int ks = 0; ks < 4; ks++) {
            f32x4 p0 = *(const f32x4*)&h1w[rbase0 + ks * 32];
            f32x4 p1 = *(const f32x4*)&h1w[rbase1 + ks * 32];
            a2[ks][0] = f2bf(p0[0]); a2[ks][1] = f2bf(p0[1]);
            a2[ks][2] = f2bf(p0[2]); a2[ks][3] = f2bf(p0[3]);
            a2[ks][4] = f2bf(p1[0]); a2[ks][5] = f2bf(p1[1]);
            a2[ks][6] = f2bf(p1[2]); a2[ks][7] = f2bf(p1[3]);
        }

        // ---- layer 2: D2[ct] = relu(h1) @ W2[:, ct*16..+16] + b2
        f32x4 d2[4];
#pragma unroll
        for (int ct = 0; ct < 4; ct++) {
            f32x4 acc = {b2v[ct], b2v[ct], b2v[ct], b2v[ct]};
#pragma unroll
            for (int ks = 0; ks < 4; ks++)
                acc = __builtin_amdgcn_mfma_f32_16x16x32_bf16(a2[ks], w2f[ct][ks], acc, 0, 0, 0);
            d2[ct] = acc;
        }

        // ---- layer 3 on VALU + 16-lane butterfly reduce + store
        float sr[4];
#pragma unroll
        for (int r = 0; r < 4; r++) {
            float s = 0.0f;
#pragma unroll
            for (int ct = 0; ct < 4; ct++)
                s = fmaf(fmaxf(d2[ct][r], 0.0f), wo[ct], s);
            sr[r] = s;
        }
#pragma unroll
        for (int m = 1; m <= 8; m <<= 1)
#pragma unroll
            for (int r = 0; r < 4; r++)
                sr[r] += __shfl_xor(sr[r], m);
        if (c == 0) {
            float4 o = {sr[0] + bo, sr[1] + bo, sr[2] + bo, sr[3] + bo};
            *(float4*)(out + tile * 16 + g * 4) = o;
        }
    }
}

extern "C" void kernel_launch(void* const* d_in, const int* in_sizes, int n_in,
                              void* d_out, int out_size, void* d_ws, size_t ws_size,
                              hipStream_t stream) {
    const float* X    = (const float*)d_in[0];
    const int*   z0   = (const int*)d_in[1];
    const int*   z1   = (const int*)d_in[2];
    const float* emb0 = (const float*)d_in[3];
    const float* emb1 = (const float*)d_in[4];
    const float* W1   = (const float*)d_in[5];
    const float* b1   = (const float*)d_in[6];
    const float* W2   = (const float*)d_in[7];
    const float* b2   = (const float*)d_in[8];
    const float* Wout = (const float*)d_in[9];
    const float* bout = (const float*)d_in[10];
    float* out = (float*)d_out;
    float* ws  = (float*)d_ws;

    // Deterministic host-side replica count from ws_size: 8 -> 4 -> 2 -> 1.
    int R = 1;
    while (R < 8 && (size_t)(R * 2) * WS_FLOATS * sizeof(float) <= ws_size) R <<= 1;

    zero_ws_kernel<<<2048, 256, 0, stream>>>(ws, R * WS_FLOATS);
    scatter_kernel<<<(N_ROWS * 16 + 255) / 256, 256, 0, stream>>>(emb0, emb1, z0, z1, ws, R - 1);
    finalize_kernel<<<(Q0 + Q1 + 255) / 256, 256, 0, stream>>>(ws, R);
    mlp_mfma_kernel<<<512, 256, 0, stream>>>(X, z0, z1, ws, W1, b1, W2, b2, Wout, bout, out);
}